// Round 5
// baseline (190.245 us; speedup 1.0000x reference)
//
#include <hip/hip_runtime.h>
#include <math.h>

#define NN 512
#define MM 31
#define TT 32            // M+1 tokens per node
#define EE 64            // INP = EMB = ATT
#define NREL 200
#define NMAT 201
#define SELF_LOOP 200
#define QCAP 192         // per-relation capacity (mean ~82, ~12 sigma)
#define NT 6             // 32-token tiles per relation
#define WSTR 72          // bf16 LDS row stride (16B-aligned, de-aliased banks)
#define CPAD 32          // one counter per 128B line (round-6 verified win)
#define GRID 608         // <=1024 co-resident (4/CU x 256); balances 1115/1200/512 tasks
#define NXCD 8
#define SPIN_MAX (1L << 20)

// barrier bookkeeping layout inside bars[64] (memset-zeroed each launch)
#define B_XCNT   0    // [8]  blocks per XCD (census)
#define B_REGTOT 8    // [1]  census total
#define B_XARR   16   // [16] per-stage per-XCD arrivals (stage*8 + x)
#define B_DONE   32   // [2 used] per-stage flush-done count (stage*8)
#define B_INVD   48   // [16] per-stage per-XCD go flag (stage*8 + x)

#define AADD(p, v)   __hip_atomic_fetch_add((p), (v), __ATOMIC_RELAXED, __HIP_MEMORY_SCOPE_AGENT)
#define ALOAD(p)     __hip_atomic_load((p), __ATOMIC_RELAXED, __HIP_MEMORY_SCOPE_AGENT)
#define ASTORE(p, v) __hip_atomic_store((p), (v), __ATOMIC_RELAXED, __HIP_MEMORY_SCOPE_AGENT)

typedef short  short8 __attribute__((ext_vector_type(8)));
typedef float  f32x4  __attribute__((ext_vector_type(4)));

__device__ __forceinline__ unsigned short f2bf(float f) {
    union { float f; unsigned int u; } a; a.f = f;
    unsigned int r = a.u + 0x7FFFu + ((a.u >> 16) & 1u);   // RNE
    return (unsigned short)(r >> 16);
}
__device__ __forceinline__ float bf2f(unsigned short u) {
    union { unsigned int u; float f; } a; a.u = ((unsigned int)u) << 16;
    return a.f;
}

__device__ __forceinline__ int get_xcc() {
    unsigned x;
    asm volatile("s_getreg_b32 %0, hwreg(HW_REG_XCC_ID)" : "=s"(x));
    return (int)(x & 7);
}

// Grid barrier v3: per-XCD fencing. Round-4 postmortem: 512 wbl2 + 512 inv
// per barrier serialized at the TCCs (~35us/barrier). Only ONE wbl2 per
// dirty XCD (after all its blocks arrive) and ONE inv per XCD (before its
// blocks proceed) are required; per-CU L1 needs no inv because every
// inter-phase buffer is write-then-read-once (no read-before-write lines).
// All spin loads are RELAXED agent-scope (coherent-point polls, no cache ops).
__device__ __forceinline__ void grid_barrier_v3(int* bars, int stage, int myxcc) {
    __syncthreads();                       // drains vmcnt -> block stores in L2
    if (threadIdx.x == 0) {
        long s;
        // census final? (instant after warmup — registration is at kernel start)
        s = 0;
        while (ALOAD(&bars[B_REGTOT]) < GRID) {
            if (++s > SPIN_MAX) break; __builtin_amdgcn_s_sleep(2);
        }
        const int myc = ALOAD(&bars[B_XCNT + myxcc]);
        int nx = 0;
#pragma unroll
        for (int x = 0; x < NXCD; ++x) nx += (ALOAD(&bars[B_XCNT + x]) > 0);

        const int xpos = AADD(&bars[B_XARR + stage * 8 + myxcc], 1) + 1;
        if (xpos == myc) {
            // last arriver on this XCD: all XCD-mates' stores are in this L2
            __builtin_amdgcn_fence(__ATOMIC_RELEASE, "agent");   // 1 wbl2 / XCD
            AADD(&bars[B_DONE + stage * 8], 1);
            s = 0;
            while (ALOAD(&bars[B_DONE + stage * 8]) < nx) {
                if (++s > SPIN_MAX) break; __builtin_amdgcn_s_sleep(2);
            }
            __builtin_amdgcn_fence(__ATOMIC_ACQUIRE, "agent");   // 1 inv / XCD
            ASTORE(&bars[B_INVD + stage * 8 + myxcc], 1);
        } else {
            s = 0;
            while (ALOAD(&bars[B_INVD + stage * 8 + myxcc]) == 0) {
                if (++s > SPIN_MAX) break; __builtin_amdgcn_s_sleep(2);
            }
        }
    }
    __syncthreads();
}

// ---------------------------------------------------------------------------
// One fused kernel, 3 phases separated by per-XCD-fenced grid barriers:
//   phase 1: prep — 603 weight-transpose tasks + 512 node tasks (grid-stride)
//   phase 2: proj — 1200 (relation, tile) MFMA projection tasks, zero LDS
//   phase 3: attn — 512 per-node attention tasks
// Counters + barrier words are zeroed by a preceding hipMemsetAsync.
// ---------------------------------------------------------------------------
__global__ __launch_bounds__(256, 4) void fused_kernel(
    const float* __restrict__ h, const float* __restrict__ W_self,
    const float* __restrict__ Q, const float* __restrict__ K,
    const float* __restrict__ V,
    const int* __restrict__ msg_type, const int* __restrict__ r_label_node,
    const int* __restrict__ r_label_msg, const float* __restrict__ msg,
    const float* __restrict__ ffn_w, const float* __restrict__ ffn_b,
    int* __restrict__ cnt_q, int* __restrict__ cnt_k,
    int* __restrict__ bars,
    int* __restrict__ list_q, int* __restrict__ list_k,
    unsigned short* __restrict__ wt_q, unsigned short* __restrict__ wt_k,
    unsigned short* __restrict__ wt_v,
    unsigned short* __restrict__ msg_bf, unsigned short* __restrict__ curr_bf,
    unsigned short* __restrict__ q_bf, unsigned short* __restrict__ k_bf,
    unsigned short* __restrict__ v_bf,
    float* __restrict__ out)
{
    const int bid = blockIdx.x, tid = threadIdx.x;
    const int lane = tid & 63, wave = tid >> 6;
    const int col = lane & 15, quad = lane >> 4;

    __shared__ union SM {
        unsigned short t_s[EE * WSTR];                       // 9216 B (converter)
        struct { float part[4][EE]; float c_s[EE]; } np;     // node prep
        struct { float s_s[TT][TT + 1]; float att0[TT]; float pooled[EE]; } at;
    } sm;

    // ---- XCD census (once, kernel start; finality checked in barrier) ----
    int myxcc = 0;
    if (tid == 0) {
        myxcc = get_xcc();
        AADD(&bars[B_XCNT + myxcc], 1);
        AADD(&bars[B_REGTOT], 1);
    }

    // ---------------- phase 1: prep ---------------------------------------
    for (int task = bid; task < 3 * NMAT + NN; task += GRID) {
        if (task < 3 * NMAT) {
            // ---- converter: one [64,64] f32 -> transposed bf16 Wt[a][e] ----
            const int r   = task % NMAT;
            const int mat = task / NMAT;
            const float* src = (mat == 0 ? Q : mat == 1 ? K : V) + (size_t)r * EE * EE;
            unsigned short* dst = (mat == 0 ? wt_q : mat == 1 ? wt_k : wt_v)
                                  + (size_t)r * EE * EE;
            {
                const int e = tid >> 2, aseg = (tid & 3) * 16;
                const float4* s4 = (const float4*)(src + e * EE + aseg);
                float4 f0 = s4[0], f1 = s4[1], f2 = s4[2], f3 = s4[3];
                unsigned short b[16] = {
                    f2bf(f0.x), f2bf(f0.y), f2bf(f0.z), f2bf(f0.w),
                    f2bf(f1.x), f2bf(f1.y), f2bf(f1.z), f2bf(f1.w),
                    f2bf(f2.x), f2bf(f2.y), f2bf(f2.z), f2bf(f2.w),
                    f2bf(f3.x), f2bf(f3.y), f2bf(f3.z), f2bf(f3.w) };
                unsigned short* d = &sm.t_s[e * WSTR + aseg];
                *(short8*)d = *(short8*)&b[0];
                *(short8*)(d + 8) = *(short8*)&b[8];
            }
            __syncthreads();
            {
                const int a = tid >> 2, eseg = (tid & 3) * 16;
                unsigned short o[16];
#pragma unroll
                for (int j = 0; j < 16; ++j)
                    o[j] = sm.t_s[(eseg + j) * WSTR + a];
                unsigned short* d = dst + a * EE + eseg;
                *(short8*)d = *(short8*)&o[0];
                *(short8*)(d + 8) = *(short8*)&o[8];
            }
            __syncthreads();   // protect t_s for next grid-stride task
        } else {
            // ---- node task ----
            const int n = task - 3 * NMAT;

            if (tid < MM) {
                int j  = n * MM + tid;
                int rl = r_label_msg[j];
                int p  = atomicAdd(&cnt_q[rl * CPAD], 1);
                if (p < QCAP) list_q[rl * QCAP + p] = n * TT + tid + 1;
                int mt = msg_type[j];
                int p2 = atomicAdd(&cnt_k[mt * CPAD], 1);
                if (p2 < QCAP) list_k[mt * QCAP + p2] = n * TT + tid + 1;
            } else if (tid == 63) {
                int r = r_label_node[n];
                int p = atomicAdd(&cnt_q[r * CPAD], 1);
                if (p < QCAP) list_q[r * QCAP + p] = n * TT;
            }

            // msg[n] -> bf16 (threads 0..247, 8 floats each, coalesced)
            if (tid < MM * EE / 8) {
                const float4* s4 = (const float4*)(msg + (size_t)n * MM * EE) + tid * 2;
                float4 f0 = s4[0], f1 = s4[1];
                unsigned short b[8] = { f2bf(f0.x), f2bf(f0.y), f2bf(f0.z), f2bf(f0.w),
                                        f2bf(f1.x), f2bf(f1.y), f2bf(f1.z), f2bf(f1.w) };
                *(short8*)(msg_bf + (size_t)n * MM * EE + tid * 8) = *(short8*)b;
            }

            // curr = h[n] @ W_self : all 256 threads, 4-way split over e
            const int c = tid & 63, part = tid >> 6;
            {
                const float* hrow = h + n * EE;
                float acc = 0.f;
#pragma unroll
                for (int e = 0; e < 16; ++e)
                    acc = fmaf(hrow[part * 16 + e], W_self[(part * 16 + e) * EE + c], acc);
                sm.np.part[part][c] = acc;
            }
            __syncthreads();
            if (tid < EE) {
                float cv = sm.np.part[0][tid] + sm.np.part[1][tid]
                         + sm.np.part[2][tid] + sm.np.part[3][tid];
                curr_bf[n * EE + tid] = f2bf(cv);
                sm.np.c_s[tid] = cv;
            }
            __syncthreads();
            // k0 = curr @ K[200] : same 4-way split
            {
                const float* K200 = K + (size_t)SELF_LOOP * EE * EE;
                float acc = 0.f;
#pragma unroll
                for (int e = 0; e < 16; ++e)
                    acc = fmaf(sm.np.c_s[part * 16 + e], K200[(part * 16 + e) * EE + c], acc);
                sm.np.part[part][c] = acc;
            }
            __syncthreads();
            if (tid < EE) {
                float k0 = sm.np.part[0][tid] + sm.np.part[1][tid]
                         + sm.np.part[2][tid] + sm.np.part[3][tid];
                k_bf[(size_t)n * TT * EE + tid] = f2bf(k0);
            }
            __syncthreads();   // protect np for next grid-stride task
        }
    }
    grid_barrier_v3(bars, 0, myxcc);

    // ---------------- phase 2: proj (zero LDS, zero block syncs) -----------
    for (int task = bid; task < NREL * NT; task += GRID) {
        const int r    = task / NT;
        const int tile = task % NT;

        const int nq = min(cnt_q[r * CPAD], QCAP);
        const int nk = min(cnt_k[r * CPAD], QCAP);
        const int q0 = tile * 32;
        const bool do_q = q0 < nq;
        const bool do_k = q0 < nk;
        if (!do_q && !do_k) continue;

        const size_t wbase = (size_t)r * EE * EE;

        // ---- q/v side (wave: mtile = w&1, mat = w>>1) ----
        if (do_q) {
            const int mtile = wave & 1;
            const unsigned short* wmat = ((wave >> 1) ? wt_v : wt_q) + wbase;
            unsigned short* outp = (wave >> 1) ? v_bf : q_bf;
            const int arow = q0 + mtile * 16 + col;
            int atok = (arow < nq) ? list_q[r * QCAP + arow] : 0;
            int an = atok >> 5, at = atok & 31;
            const unsigned short* aptr = at
                ? (msg_bf + ((size_t)an * MM + (at - 1)) * EE)
                : (curr_bf + (size_t)an * EE);
            f32x4 acc[4] = {{0,0,0,0},{0,0,0,0},{0,0,0,0},{0,0,0,0}};
#pragma unroll
            for (int kk = 0; kk < 2; ++kk) {
                short8 af = *(const short8*)(aptr + kk * 32 + quad * 8);
#pragma unroll
                for (int nt = 0; nt < 4; ++nt) {
                    short8 bf = *(const short8*)(wmat + (nt * 16 + col) * EE + kk * 32 + quad * 8);
                    acc[nt] = __builtin_amdgcn_mfma_f32_16x16x32_bf16(af, bf, acc[nt], 0, 0, 0);
                }
            }
#pragma unroll
            for (int reg = 0; reg < 4; ++reg) {
                int rrow = q0 + mtile * 16 + quad * 4 + reg;
                if (rrow < nq) {
                    int token = list_q[r * QCAP + rrow];
#pragma unroll
                    for (int nt = 0; nt < 4; ++nt)
                        outp[(size_t)token * EE + nt * 16 + col] = f2bf(acc[nt][reg]);
                }
            }
        }

        // ---- k side (wave: mtile = w&1, n-half = w>>1) ----
        if (do_k) {
            const int mtile = wave & 1;
            const int nh = wave >> 1;
            const int arow = q0 + mtile * 16 + col;
            int atok = (arow < nk) ? list_k[r * QCAP + arow] : 0;
            int an = atok >> 5, at = atok & 31;
            const unsigned short* aptr = at
                ? (msg_bf + ((size_t)an * MM + (at - 1)) * EE)
                : (curr_bf + (size_t)an * EE);
            const unsigned short* wmat = wt_k + wbase;
            f32x4 acc[2] = {{0,0,0,0},{0,0,0,0}};
#pragma unroll
            for (int kk = 0; kk < 2; ++kk) {
                short8 af = *(const short8*)(aptr + kk * 32 + quad * 8);
#pragma unroll
                for (int j = 0; j < 2; ++j) {
                    int nt = nh * 2 + j;
                    short8 bf = *(const short8*)(wmat + (nt * 16 + col) * EE + kk * 32 + quad * 8);
                    acc[j] = __builtin_amdgcn_mfma_f32_16x16x32_bf16(af, bf, acc[j], 0, 0, 0);
                }
            }
#pragma unroll
            for (int reg = 0; reg < 4; ++reg) {
                int rrow = q0 + mtile * 16 + quad * 4 + reg;
                if (rrow < nk) {
                    int token = list_k[r * QCAP + rrow];
#pragma unroll
                    for (int j = 0; j < 2; ++j)
                        k_bf[(size_t)token * EE + (nh * 2 + j) * 16 + col] = f2bf(acc[j][reg]);
                }
            }
        }
    }
    grid_barrier_v3(bars, 1, myxcc);

    // ---------------- phase 3: attn ---------------------------------------
    for (int task = bid; task < NN; task += GRID) {
        const int n = task;

        {   // scores: wave w -> tile (mi = w&1, ni = w>>1), direct-global MFMA
            const int mi = wave & 1, ni = wave >> 1;
            const unsigned short* qrow = q_bf + ((size_t)n * TT + mi * 16 + col) * EE;
            const unsigned short* krow = k_bf + ((size_t)n * TT + ni * 16 + col) * EE;
            f32x4 acc = {0, 0, 0, 0};
#pragma unroll
            for (int kk = 0; kk < 2; ++kk) {
                short8 a = *(const short8*)(qrow + kk * 32 + quad * 8);
                short8 b = *(const short8*)(krow + kk * 32 + quad * 8);
                acc = __builtin_amdgcn_mfma_f32_16x16x32_bf16(a, b, acc, 0, 0, 0);
            }
#pragma unroll
            for (int reg = 0; reg < 4; ++reg)
                sm.at.s_s[mi * 16 + quad * 4 + reg][ni * 16 + col] = acc[reg] * 0.125f;
        }
        __syncthreads();

        // softmax over the QUERY axis per column; only row 0 of att needed
        if (tid < TT) {
            float mx = -INFINITY;
#pragma unroll
            for (int qi = 0; qi < TT; ++qi) mx = fmaxf(mx, sm.at.s_s[qi][tid]);
            float sum = 0.f;
#pragma unroll
            for (int qi = 0; qi < TT; ++qi) sum += __expf(sm.at.s_s[qi][tid] - mx);
            sm.at.att0[tid] = __expf(sm.at.s_s[0][tid] - mx) / sum;
        }
        __syncthreads();

        if (tid < EE) {
            const unsigned short* vp = v_bf + (size_t)n * TT * EE + tid;
            float acc = 0.f;
#pragma unroll 8
            for (int ki = 0; ki < TT; ++ki)
                acc = fmaf(sm.at.att0[ki], bf2f(vp[ki * EE]), acc);
            sm.at.pooled[tid] = acc;
        }
        __syncthreads();

        if (tid < EE) {
            float acc = ffn_b[tid];
#pragma unroll 8
            for (int a = 0; a < EE; ++a)
                acc = fmaf(sm.at.pooled[a], ffn_w[a * EE + tid], acc);
            out[n * EE + tid] = acc;
        }
        __syncthreads();
    }
}

extern "C" void kernel_launch(void* const* d_in, const int* in_sizes, int n_in,
                              void* d_out, int out_size, void* d_ws, size_t ws_size,
                              hipStream_t stream) {
    const float* h            = (const float*)d_in[0];
    const float* msg          = (const float*)d_in[1];
    const int*   msg_type     = (const int*)  d_in[2];
    const int*   r_label_node = (const int*)  d_in[3];
    const int*   r_label_msg  = (const int*)  d_in[4];
    const float* W_self       = (const float*)d_in[5];
    const float* Q            = (const float*)d_in[6];
    const float* K            = (const float*)d_in[7];
    const float* V            = (const float*)d_in[8];
    const float* ffn_w        = (const float*)d_in[9];
    const float* ffn_b        = (const float*)d_in[10];
    float*       out          = (float*)d_out;

    // ws layout (16B aligned): counters | barrier words | lists | bf16 data
    int* cnt_q  = (int*)d_ws;                          // [200*CPAD]
    int* cnt_k  = cnt_q + NREL * CPAD;                 // [200*CPAD]
    int* bars   = cnt_k + NREL * CPAD;                 // [64] barrier bookkeeping
    int* list_q = bars + 64;                           // [200*QCAP]
    int* list_k = list_q + NREL * QCAP;                // [200*QCAP]
    unsigned short* wt_q = (unsigned short*)(list_k + NREL * QCAP);
    unsigned short* wt_k = wt_q + (size_t)NMAT * EE * EE;
    unsigned short* wt_v = wt_k + (size_t)NMAT * EE * EE;
    unsigned short* msg_bf  = wt_v + (size_t)NMAT * EE * EE;     // [512*31*64]
    unsigned short* curr_bf = msg_bf + (size_t)NN * MM * EE;     // [512*64]
    unsigned short* q_bf = curr_bf + NN * EE;                    // [512*32*64]
    unsigned short* k_bf = q_bf + (size_t)NN * TT * EE;
    unsigned short* v_bf = k_bf + (size_t)NN * TT * EE;

    // zero counters + barrier words in one small memset
    hipMemsetAsync(cnt_q, 0, (2 * NREL * CPAD + 64) * sizeof(int), stream);
    fused_kernel<<<GRID, 256, 0, stream>>>(
        h, W_self, Q, K, V, msg_type, r_label_node, r_label_msg, msg,
        ffn_w, ffn_b,
        cnt_q, cnt_k, bars, list_q, list_k, wt_q, wt_k, wt_v,
        msg_bf, curr_bf, q_bf, k_bf, v_bf, out);
}

// Round 6
// 110.553 us; speedup vs baseline: 1.7209x; 1.7209x over previous
//
#include <hip/hip_runtime.h>
#include <math.h>

#define NN 512
#define MM 31
#define TT 32            // M+1 tokens per node
#define EE 64            // INP = EMB = ATT
#define NREL 200
#define NMAT 201
#define SELF_LOOP 200
#define QCAP 192         // per-relation capacity (mean ~82, ~12 sigma)
#define NT 6             // 32-token tiles per relation
#define WSTR 72          // bf16 LDS row stride (16B-aligned, de-aliased banks)
#define CPAD 32          // one counter per 128B line
#define GRID 1024        // EXACTLY the co-resident capacity (4/CU x 256 CU)
#define NXCD 8
#define BLKS_PER_XCD 128 // 1024 blocks fill all slots -> 32 CU x 4 per XCD
#define SPIN_MAX (1L << 17)
#define NBARS 1152       // barrier slots, each used word 128B apart

// bars layout (all used words at idx*32 -> distinct 128B lines):
//   XARR[s][x] = bars[(s*8+x)*32]        s<2, x<8   (arrival counts)
//   DONE[s]    = bars[512 + s*32]                   (flush-done count)
//   GO[s][x]   = bars[576 + (s*8+x)*32]             (per-XCD go flag)

#define AADD(p, v)   __hip_atomic_fetch_add((p), (v), __ATOMIC_RELAXED, __HIP_MEMORY_SCOPE_AGENT)
#define ALOAD(p)     __hip_atomic_load((p), __ATOMIC_RELAXED, __HIP_MEMORY_SCOPE_AGENT)
#define ASTORE(p, v) __hip_atomic_store((p), (v), __ATOMIC_RELAXED, __HIP_MEMORY_SCOPE_AGENT)

typedef short  short8 __attribute__((ext_vector_type(8)));
typedef float  f32x4  __attribute__((ext_vector_type(4)));

__device__ __forceinline__ unsigned short f2bf(float f) {
    union { float f; unsigned int u; } a; a.f = f;
    unsigned int r = a.u + 0x7FFFu + ((a.u >> 16) & 1u);   // RNE
    return (unsigned short)(r >> 16);
}
__device__ __forceinline__ float bf2f(unsigned short u) {
    union { unsigned int u; float f; } a; a.u = ((unsigned int)u) << 16;
    return a.f;
}

// Grid barrier v4 (round-5 postmortem): fence COUNT was irrelevant (512 vs 8
// fences tied); the cost model now blames the ACQUIRE buffer_inv (whole-L2
// invalidate -> post-barrier phases run on cold L2, pure miss latency).
// v4 drops the acquire entirely: legal because every inter-phase buffer is
// single-writer-line write-then-read (reader XCD either wrote the line ->
// valid in its L2, or never touched it -> clean miss -> LLC has the flushed
// copy). Multi-XCD-written lines (lists/counters) are read with RELAXED
// agent atomics (coherent-point loads) instead. Release wbl2 stays: one per
// XCD, by the last arriver (captain). Exactly-128-blocks-per-XCD is forced
// by LDS-capped occupancy (36KB -> 4 blocks/CU, GRID == capacity).
__device__ __forceinline__ void grid_barrier_v4(int* bars, int stage) {
    __syncthreads();                       // drains vmcnt: block stores in L2
    if (threadIdx.x == 0) {
        int x;
        asm volatile("s_getreg_b32 %0, hwreg(HW_REG_XCC_ID)" : "=s"(x));
        x &= 7;
        const int pos = AADD(&bars[(stage * 8 + x) * 32], 1);
        if (pos == BLKS_PER_XCD - 1) {
            // captain: all XCD-mates arrived; flush this XCD's dirty L2 -> LLC
            __builtin_amdgcn_fence(__ATOMIC_RELEASE, "agent");   // 1 wbl2/XCD
            AADD(&bars[512 + stage * 32], 1);
            long s = 0;
            while (ALOAD(&bars[512 + stage * 32]) < NXCD) {
                __builtin_amdgcn_s_sleep(4);
                if (++s > SPIN_MAX) break;
            }
            ASTORE(&bars[576 + (stage * 8 + x) * 32], 1);
        } else {
            long s = 0;
            while (ALOAD(&bars[576 + (stage * 8 + x) * 32]) == 0) {
                __builtin_amdgcn_s_sleep(8);
                if (++s > SPIN_MAX) break;
            }
        }
    }
    __syncthreads();
    asm volatile("" ::: "memory");         // compiler fence only (no cache ops)
}

// ---------------------------------------------------------------------------
// One fused kernel, 3 phases separated by release-only grid barriers:
//   phase 1: prep — 603 weight-transpose tasks + 512 node tasks (grid-stride)
//   phase 2: proj — 1200 (relation, tile) MFMA tasks (lists via LDS staging)
//   phase 3: attn — 512 per-node attention tasks
// Counters + barrier words are zeroed by a preceding hipMemsetAsync.
// ---------------------------------------------------------------------------
__global__ __launch_bounds__(256, 4) void fused_kernel(
    const float* __restrict__ h, const float* __restrict__ W_self,
    const float* __restrict__ Q, const float* __restrict__ K,
    const float* __restrict__ V,
    const int* __restrict__ msg_type, const int* __restrict__ r_label_node,
    const int* __restrict__ r_label_msg, const float* __restrict__ msg,
    const float* __restrict__ ffn_w, const float* __restrict__ ffn_b,
    int* __restrict__ cnt_q, int* __restrict__ cnt_k,
    int* __restrict__ bars,
    int* __restrict__ list_q, int* __restrict__ list_k,
    unsigned short* __restrict__ wt_q, unsigned short* __restrict__ wt_k,
    unsigned short* __restrict__ wt_v,
    unsigned short* __restrict__ msg_bf, unsigned short* __restrict__ curr_bf,
    unsigned short* __restrict__ q_bf, unsigned short* __restrict__ k_bf,
    unsigned short* __restrict__ v_bf,
    float* __restrict__ out)
{
    const int bid = blockIdx.x, tid = threadIdx.x;
    const int lane = tid & 63, wave = tid >> 6;
    const int col = lane & 15, quad = lane >> 4;

    __shared__ union SM {
        unsigned short t_s[EE * WSTR];                       // 9216 B (converter)
        struct { float part[4][EE]; float c_s[EE]; } np;     // node prep
        struct { int tq[32]; int tk[32]; } pj;               // proj list staging
        struct { float s_s[TT][TT + 1]; float att0[TT]; float pooled[EE]; } at;
        unsigned char occupancy_pad[36864];  // force 4 blocks/CU (160/36=4.4)
    } sm;

    // ---------------- phase 1: prep ---------------------------------------
    for (int task = bid; task < 3 * NMAT + NN; task += GRID) {
        if (task < 3 * NMAT) {
            // ---- converter: one [64,64] f32 -> transposed bf16 Wt[a][e] ----
            const int r   = task % NMAT;
            const int mat = task / NMAT;
            const float* src = (mat == 0 ? Q : mat == 1 ? K : V) + (size_t)r * EE * EE;
            unsigned short* dst = (mat == 0 ? wt_q : mat == 1 ? wt_k : wt_v)
                                  + (size_t)r * EE * EE;
            {
                const int e = tid >> 2, aseg = (tid & 3) * 16;
                const float4* s4 = (const float4*)(src + e * EE + aseg);
                float4 f0 = s4[0], f1 = s4[1], f2 = s4[2], f3 = s4[3];
                unsigned short b[16] = {
                    f2bf(f0.x), f2bf(f0.y), f2bf(f0.z), f2bf(f0.w),
                    f2bf(f1.x), f2bf(f1.y), f2bf(f1.z), f2bf(f1.w),
                    f2bf(f2.x), f2bf(f2.y), f2bf(f2.z), f2bf(f2.w),
                    f2bf(f3.x), f2bf(f3.y), f2bf(f3.z), f2bf(f3.w) };
                unsigned short* d = &sm.t_s[e * WSTR + aseg];
                *(short8*)d = *(short8*)&b[0];
                *(short8*)(d + 8) = *(short8*)&b[8];
            }
            __syncthreads();
            {
                const int a = tid >> 2, eseg = (tid & 3) * 16;
                unsigned short o[16];
#pragma unroll
                for (int j = 0; j < 16; ++j)
                    o[j] = sm.t_s[(eseg + j) * WSTR + a];
                unsigned short* d = dst + a * EE + eseg;
                *(short8*)d = *(short8*)&o[0];
                *(short8*)(d + 8) = *(short8*)&o[8];
            }
            __syncthreads();   // protect t_s for next grid-stride task
        } else {
            // ---- node task ----
            const int n = task - 3 * NMAT;

            if (tid < MM) {
                int j  = n * MM + tid;
                int rl = r_label_msg[j];
                int p  = atomicAdd(&cnt_q[rl * CPAD], 1);
                if (p < QCAP) list_q[rl * QCAP + p] = n * TT + tid + 1;
                int mt = msg_type[j];
                int p2 = atomicAdd(&cnt_k[mt * CPAD], 1);
                if (p2 < QCAP) list_k[mt * QCAP + p2] = n * TT + tid + 1;
            } else if (tid == 63) {
                int r = r_label_node[n];
                int p = atomicAdd(&cnt_q[r * CPAD], 1);
                if (p < QCAP) list_q[r * QCAP + p] = n * TT;
            }

            // msg[n] -> bf16 (threads 0..247, 8 floats each, coalesced)
            if (tid < MM * EE / 8) {
                const float4* s4 = (const float4*)(msg + (size_t)n * MM * EE) + tid * 2;
                float4 f0 = s4[0], f1 = s4[1];
                unsigned short b[8] = { f2bf(f0.x), f2bf(f0.y), f2bf(f0.z), f2bf(f0.w),
                                        f2bf(f1.x), f2bf(f1.y), f2bf(f1.z), f2bf(f1.w) };
                *(short8*)(msg_bf + (size_t)n * MM * EE + tid * 8) = *(short8*)b;
            }

            // curr = h[n] @ W_self : all 256 threads, 4-way split over e
            const int c = tid & 63, part = tid >> 6;
            {
                const float* hrow = h + n * EE;
                float acc = 0.f;
#pragma unroll
                for (int e = 0; e < 16; ++e)
                    acc = fmaf(hrow[part * 16 + e], W_self[(part * 16 + e) * EE + c], acc);
                sm.np.part[part][c] = acc;
            }
            __syncthreads();
            if (tid < EE) {
                float cv = sm.np.part[0][tid] + sm.np.part[1][tid]
                         + sm.np.part[2][tid] + sm.np.part[3][tid];
                curr_bf[n * EE + tid] = f2bf(cv);
                sm.np.c_s[tid] = cv;
            }
            __syncthreads();
            // k0 = curr @ K[200] : same 4-way split
            {
                const float* K200 = K + (size_t)SELF_LOOP * EE * EE;
                float acc = 0.f;
#pragma unroll
                for (int e = 0; e < 16; ++e)
                    acc = fmaf(sm.np.c_s[part * 16 + e], K200[(part * 16 + e) * EE + c], acc);
                sm.np.part[part][c] = acc;
            }
            __syncthreads();
            if (tid < EE) {
                float k0 = sm.np.part[0][tid] + sm.np.part[1][tid]
                         + sm.np.part[2][tid] + sm.np.part[3][tid];
                k_bf[(size_t)n * TT * EE + tid] = f2bf(k0);
            }
            __syncthreads();   // protect np for next grid-stride task
        }
    }
    grid_barrier_v4(bars, 0);

    // ---------------- phase 2: proj ----------------------------------------
    // lists/counters are multi-XCD-written: read via RELAXED agent atomics
    // (coherent point), staged once per task into LDS. Everything else is
    // single-writer-line and read with plain loads (L2-warm, no inv needed).
    for (int task = bid; task < NREL * NT; task += GRID) {
        const int r    = task / NT;
        const int tile = task % NT;

        const int nq = min(ALOAD(&cnt_q[r * CPAD]), QCAP);
        const int nk = min(ALOAD(&cnt_k[r * CPAD]), QCAP);
        const int q0 = tile * 32;
        const bool do_q = q0 < nq;
        const bool do_k = q0 < nk;
        if (!do_q && !do_k) continue;

        if (tid < 32) {
            sm.pj.tq[tid] = (do_q && q0 + tid < nq)
                ? ALOAD(&list_q[r * QCAP + q0 + tid]) : -1;
        } else if (tid < 64) {
            int i = tid - 32;
            sm.pj.tk[i] = (do_k && q0 + i < nk)
                ? ALOAD(&list_k[r * QCAP + q0 + i]) : -1;
        }
        __syncthreads();

        const size_t wbase = (size_t)r * EE * EE;

        // ---- q/v side (wave: mtile = w&1, mat = w>>1) ----
        if (do_q) {
            const int mtile = wave & 1;
            const unsigned short* wmat = ((wave >> 1) ? wt_v : wt_q) + wbase;
            unsigned short* outp = (wave >> 1) ? v_bf : q_bf;
            int t0 = sm.pj.tq[mtile * 16 + col];
            int atok = t0 < 0 ? 0 : t0;
            int an = atok >> 5, at = atok & 31;
            const unsigned short* aptr = at
                ? (msg_bf + ((size_t)an * MM + (at - 1)) * EE)
                : (curr_bf + (size_t)an * EE);
            f32x4 acc[4] = {{0,0,0,0},{0,0,0,0},{0,0,0,0},{0,0,0,0}};
#pragma unroll
            for (int kk = 0; kk < 2; ++kk) {
                short8 af = *(const short8*)(aptr + kk * 32 + quad * 8);
#pragma unroll
                for (int nt = 0; nt < 4; ++nt) {
                    short8 bf = *(const short8*)(wmat + (nt * 16 + col) * EE + kk * 32 + quad * 8);
                    acc[nt] = __builtin_amdgcn_mfma_f32_16x16x32_bf16(af, bf, acc[nt], 0, 0, 0);
                }
            }
#pragma unroll
            for (int reg = 0; reg < 4; ++reg) {
                int token = sm.pj.tq[mtile * 16 + quad * 4 + reg];
                if (token >= 0) {
#pragma unroll
                    for (int nt = 0; nt < 4; ++nt)
                        outp[(size_t)token * EE + nt * 16 + col] = f2bf(acc[nt][reg]);
                }
            }
        }

        // ---- k side (wave: mtile = w&1, n-half = w>>1) ----
        if (do_k) {
            const int mtile = wave & 1;
            const int nh = wave >> 1;
            int t0 = sm.pj.tk[mtile * 16 + col];
            int atok = t0 < 0 ? 0 : t0;
            int an = atok >> 5, at = atok & 31;
            const unsigned short* aptr = at
                ? (msg_bf + ((size_t)an * MM + (at - 1)) * EE)
                : (curr_bf + (size_t)an * EE);
            const unsigned short* wmat = wt_k + wbase;
            f32x4 acc[2] = {{0,0,0,0},{0,0,0,0}};
#pragma unroll
            for (int kk = 0; kk < 2; ++kk) {
                short8 af = *(const short8*)(aptr + kk * 32 + quad * 8);
#pragma unroll
                for (int j = 0; j < 2; ++j) {
                    int nt = nh * 2 + j;
                    short8 bf = *(const short8*)(wmat + (nt * 16 + col) * EE + kk * 32 + quad * 8);
                    acc[j] = __builtin_amdgcn_mfma_f32_16x16x32_bf16(af, bf, acc[j], 0, 0, 0);
                }
            }
#pragma unroll
            for (int reg = 0; reg < 4; ++reg) {
                int token = sm.pj.tk[mtile * 16 + quad * 4 + reg];
                if (token >= 0) {
#pragma unroll
                    for (int j = 0; j < 2; ++j)
                        k_bf[(size_t)token * EE + (nh * 2 + j) * 16 + col] = f2bf(acc[j][reg]);
                }
            }
        }
        __syncthreads();   // protect pj staging for next grid-stride task
    }
    grid_barrier_v4(bars, 1);

    // ---------------- phase 3: attn ---------------------------------------
    for (int task = bid; task < NN; task += GRID) {
        const int n = task;

        {   // scores: wave w -> tile (mi = w&1, ni = w>>1), direct-global MFMA
            const int mi = wave & 1, ni = wave >> 1;
            const unsigned short* qrow = q_bf + ((size_t)n * TT + mi * 16 + col) * EE;
            const unsigned short* krow = k_bf + ((size_t)n * TT + ni * 16 + col) * EE;
            f32x4 acc = {0, 0, 0, 0};
#pragma unroll
            for (int kk = 0; kk < 2; ++kk) {
                short8 a = *(const short8*)(qrow + kk * 32 + quad * 8);
                short8 b = *(const short8*)(krow + kk * 32 + quad * 8);
                acc = __builtin_amdgcn_mfma_f32_16x16x32_bf16(a, b, acc, 0, 0, 0);
            }
#pragma unroll
            for (int reg = 0; reg < 4; ++reg)
                sm.at.s_s[mi * 16 + quad * 4 + reg][ni * 16 + col] = acc[reg] * 0.125f;
        }
        __syncthreads();

        // softmax over the QUERY axis per column; only row 0 of att needed
        if (tid < TT) {
            float mx = -INFINITY;
#pragma unroll
            for (int qi = 0; qi < TT; ++qi) mx = fmaxf(mx, sm.at.s_s[qi][tid]);
            float sum = 0.f;
#pragma unroll
            for (int qi = 0; qi < TT; ++qi) sum += __expf(sm.at.s_s[qi][tid] - mx);
            sm.at.att0[tid] = __expf(sm.at.s_s[0][tid] - mx) / sum;
        }
        __syncthreads();

        if (tid < EE) {
            const unsigned short* vp = v_bf + (size_t)n * TT * EE + tid;
            float acc = 0.f;
#pragma unroll 8
            for (int ki = 0; ki < TT; ++ki)
                acc = fmaf(sm.at.att0[ki], bf2f(vp[ki * EE]), acc);
            sm.at.pooled[tid] = acc;
        }
        __syncthreads();

        if (tid < EE) {
            float acc = ffn_b[tid];
#pragma unroll 8
            for (int a = 0; a < EE; ++a)
                acc = fmaf(sm.at.pooled[a], ffn_w[a * EE + tid], acc);
            out[n * EE + tid] = acc;
        }
        __syncthreads();
    }
}

extern "C" void kernel_launch(void* const* d_in, const int* in_sizes, int n_in,
                              void* d_out, int out_size, void* d_ws, size_t ws_size,
                              hipStream_t stream) {
    const float* h            = (const float*)d_in[0];
    const float* msg          = (const float*)d_in[1];
    const int*   msg_type     = (const int*)  d_in[2];
    const int*   r_label_node = (const int*)  d_in[3];
    const int*   r_label_msg  = (const int*)  d_in[4];
    const float* W_self       = (const float*)d_in[5];
    const float* Q            = (const float*)d_in[6];
    const float* K            = (const float*)d_in[7];
    const float* V            = (const float*)d_in[8];
    const float* ffn_w        = (const float*)d_in[9];
    const float* ffn_b        = (const float*)d_in[10];
    float*       out          = (float*)d_out;

    // ws layout (16B aligned): counters | barrier words | lists | bf16 data
    int* cnt_q  = (int*)d_ws;                          // [200*CPAD]
    int* cnt_k  = cnt_q + NREL * CPAD;                 // [200*CPAD]
    int* bars   = cnt_k + NREL * CPAD;                 // [NBARS]
    int* list_q = bars + NBARS;                        // [200*QCAP]
    int* list_k = list_q + NREL * QCAP;                // [200*QCAP]
    unsigned short* wt_q = (unsigned short*)(list_k + NREL * QCAP);
    unsigned short* wt_k = wt_q + (size_t)NMAT * EE * EE;
    unsigned short* wt_v = wt_k + (size_t)NMAT * EE * EE;
    unsigned short* msg_bf  = wt_v + (size_t)NMAT * EE * EE;     // [512*31*64]
    unsigned short* curr_bf = msg_bf + (size_t)NN * MM * EE;     // [512*64]
    unsigned short* q_bf = curr_bf + NN * EE;                    // [512*32*64]
    unsigned short* k_bf = q_bf + (size_t)NN * TT * EE;
    unsigned short* v_bf = k_bf + (size_t)NN * TT * EE;

    // zero counters + barrier words in one small memset
    hipMemsetAsync(cnt_q, 0, (2 * NREL * CPAD + NBARS) * sizeof(int), stream);
    fused_kernel<<<GRID, 256, 0, stream>>>(
        h, W_self, Q, K, V, msg_type, r_label_node, r_label_msg, msg,
        ffn_w, ffn_b,
        cnt_q, cnt_k, bars, list_q, list_k, wt_q, wt_k, wt_v,
        msg_bf, curr_bf, q_bf, k_bf, v_bf, out);
}

// Round 7
// 108.718 us; speedup vs baseline: 1.7499x; 1.0169x over previous
//
#include <hip/hip_runtime.h>
#include <math.h>

#define NN 512
#define MM 31
#define TT 32            // M+1 tokens per node
#define EE 64            // INP = EMB = ATT
#define NREL 200
#define NMAT 201
#define SELF_LOOP 200
#define QCAP 192         // per-relation capacity (mean ~82, ~12 sigma)
#define NT 6             // 32-token tiles per relation
#define WSTR 72          // bf16 LDS row stride (16B-aligned, de-aliased banks)
#define CPAD 32          // one counter per 128B line (round-6 verified win)

typedef short  short8 __attribute__((ext_vector_type(8)));
typedef float  f32x4  __attribute__((ext_vector_type(4)));

__device__ __forceinline__ unsigned short f2bf(float f) {
    union { float f; unsigned int u; } a; a.f = f;
    unsigned int r = a.u + 0x7FFFu + ((a.u >> 16) & 1u);   // RNE
    return (unsigned short)(r >> 16);
}
__device__ __forceinline__ float bf2f(unsigned short u) {
    union { unsigned int u; float f; } a; a.u = ((unsigned int)u) << 16;
    return a.f;
}

// ---------------------------------------------------------------------------
// prep_convert: grid = 603 converter blocks + 512 node blocks.
//  bid < 603:  one [64,64] f32 Q/K/V matrix -> transposed bf16 Wt[a][e]
//  bid >= 603: node n: scan labels into buckets (padded counters),
//              curr = h@W_self -> f32, k[n][0] = curr@K[200] -> bf16.
//  (round-7 change: NO msg pass here — proj converts msg f32 on the fly.)
// ---------------------------------------------------------------------------
__global__ __launch_bounds__(256) void prep_convert_kernel(
    const float* __restrict__ h, const float* __restrict__ W_self,
    const float* __restrict__ Q, const float* __restrict__ K,
    const float* __restrict__ V,
    const int* __restrict__ msg_type, const int* __restrict__ r_label_node,
    const int* __restrict__ r_label_msg,
    int* __restrict__ cnt_q, int* __restrict__ cnt_k,
    int* __restrict__ list_q, int* __restrict__ list_k,
    unsigned short* __restrict__ wt_q, unsigned short* __restrict__ wt_k,
    unsigned short* __restrict__ wt_v,
    float* __restrict__ curr_f, unsigned short* __restrict__ k_bf)
{
    const int bid = blockIdx.x, tid = threadIdx.x;

    if (bid < 3 * NMAT) {
        // ---- converter: one [64,64] f32 -> transposed bf16 Wt[a][e] ----
        const int r   = bid % NMAT;
        const int mat = bid / NMAT;
        const float* src = (mat == 0 ? Q : mat == 1 ? K : V) + (size_t)r * EE * EE;
        unsigned short* dst = (mat == 0 ? wt_q : mat == 1 ? wt_k : wt_v)
                              + (size_t)r * EE * EE;
        __shared__ unsigned short t_s[EE * WSTR];
        {
            const int e = tid >> 2, aseg = (tid & 3) * 16;
            const float4* s4 = (const float4*)(src + e * EE + aseg);
            float4 f0 = s4[0], f1 = s4[1], f2 = s4[2], f3 = s4[3];
            unsigned short b[16] = {
                f2bf(f0.x), f2bf(f0.y), f2bf(f0.z), f2bf(f0.w),
                f2bf(f1.x), f2bf(f1.y), f2bf(f1.z), f2bf(f1.w),
                f2bf(f2.x), f2bf(f2.y), f2bf(f2.z), f2bf(f2.w),
                f2bf(f3.x), f2bf(f3.y), f2bf(f3.z), f2bf(f3.w) };
            unsigned short* d = &t_s[e * WSTR + aseg];
            *(short8*)d = *(short8*)&b[0];
            *(short8*)(d + 8) = *(short8*)&b[8];
        }
        __syncthreads();
        {
            const int a = tid >> 2, eseg = (tid & 3) * 16;
            unsigned short o[16];
#pragma unroll
            for (int j = 0; j < 16; ++j)
                o[j] = t_s[(eseg + j) * WSTR + a];
            unsigned short* d = dst + a * EE + eseg;
            *(short8*)d = *(short8*)&o[0];
            *(short8*)(d + 8) = *(short8*)&o[8];
        }
        return;
    }

    // ---- node block ----
    const int n = bid - 3 * NMAT;

    // scan labels into padded relation buckets
    if (tid < MM) {
        int j  = n * MM + tid;
        int rl = r_label_msg[j];
        int p  = atomicAdd(&cnt_q[rl * CPAD], 1);
        if (p < QCAP) list_q[rl * QCAP + p] = n * TT + tid + 1;
        int mt = msg_type[j];
        int p2 = atomicAdd(&cnt_k[mt * CPAD], 1);
        if (p2 < QCAP) list_k[mt * QCAP + p2] = n * TT + tid + 1;
    } else if (tid == 63) {
        int r = r_label_node[n];
        int p = atomicAdd(&cnt_q[r * CPAD], 1);
        if (p < QCAP) list_q[r * QCAP + p] = n * TT;
    }

    // curr = h[n] @ W_self (f32 accum), publish f32; k0 = curr @ K[200]
    __shared__ float c_s[EE];
    if (tid < EE) {
        const float* hrow = h + n * EE;
        float acc = 0.f;
#pragma unroll 8
        for (int e = 0; e < EE; ++e)
            acc = fmaf(hrow[e], W_self[e * EE + tid], acc);
        curr_f[n * EE + tid] = acc;
        c_s[tid] = acc;
    }
    __syncthreads();
    if (tid < EE) {
        const float* K200 = K + (size_t)SELF_LOOP * EE * EE;
        float k0 = 0.f;
#pragma unroll 8
        for (int e = 0; e < EE; ++e)
            k0 = fmaf(c_s[e], K200[e * EE + tid], k0);
        k_bf[(size_t)n * TT * EE + tid] = f2bf(k0);
    }
}

// ---------------------------------------------------------------------------
// proj_tile: block = (relation r, tile t). 32 q-tokens AND 32 k-tokens via
// 16x16x32 bf16 MFMA. Weights staged as pure bf16 copies; x rows staged
// from f32 source (msg / curr_f) with in-flight f2bf conversion (round-7:
// moves the conversion to the latency-bound consumer, deleting prep's 6MB
// msg pass; numerics bit-identical).
//   A[m=lane&15][k=(lane>>4)*8+j], B[k][n=lane&15] from Wt[a=n][e=k],
//   C: col=lane&15, row=(lane>>4)*4+reg  (verified rounds 3-7)
// ---------------------------------------------------------------------------
__global__ __launch_bounds__(256) void proj_tile_kernel(
    const float* __restrict__ curr_f,
    const float* __restrict__ msg,
    const unsigned short* __restrict__ wt_q,
    const unsigned short* __restrict__ wt_k,
    const unsigned short* __restrict__ wt_v,
    const int* __restrict__ cnt_q, const int* __restrict__ cnt_k,
    const int* __restrict__ list_q, const int* __restrict__ list_k,
    unsigned short* __restrict__ q_bf, unsigned short* __restrict__ k_bf,
    unsigned short* __restrict__ v_bf)
{
    const int r    = blockIdx.x / NT;
    const int tile = blockIdx.x % NT;
    const int tid  = threadIdx.x;
    const int lane = tid & 63;
    const int wave = tid >> 6;
    const int col  = lane & 15;
    const int quad = lane >> 4;

    const int nq = min(cnt_q[r * CPAD], QCAP);
    const int nk = min(cnt_k[r * CPAD], QCAP);
    const int q0 = tile * 32;
    const bool do_q = q0 < nq;
    const bool do_k = q0 < nk;
    if (!do_q && !do_k) return;

    __shared__ unsigned short wq_s[EE * WSTR];
    __shared__ unsigned short wk_s[EE * WSTR];
    __shared__ unsigned short wv_s[EE * WSTR];
    __shared__ unsigned short x_s[64 * WSTR];   // 0..31 q-side, 32..63 k-side
    __shared__ int tq_s[32], tk_s[32];

    // ---- stage weights: pure bf16 copy ----
    {
        const int a = tid >> 2, seg = (tid & 3) * 16;
        const size_t go = (size_t)r * EE * EE + a * EE + seg;
        const int lo = a * WSTR + seg;
        if (do_q) {
            short8 w0 = *(const short8*)(wt_q + go);
            short8 w1 = *(const short8*)(wt_q + go + 8);
            *(short8*)&wq_s[lo] = w0; *(short8*)&wq_s[lo + 8] = w1;
            short8 v0 = *(const short8*)(wt_v + go);
            short8 v1 = *(const short8*)(wt_v + go + 8);
            *(short8*)&wv_s[lo] = v0; *(short8*)&wv_s[lo + 8] = v1;
        }
        if (do_k) {
            short8 k0_ = *(const short8*)(wt_k + go);
            short8 k1_ = *(const short8*)(wt_k + go + 8);
            *(short8*)&wk_s[lo] = k0_; *(short8*)&wk_s[lo + 8] = k1_;
        }
    }

    if (tid < 32) {
        tq_s[tid] = (do_q && q0 + tid < nq) ? list_q[r * QCAP + q0 + tid] : -1;
    } else if (tid < 64) {
        int i = tid - 32;
        tk_s[i] = (do_k && q0 + i < nk) ? list_k[r * QCAP + q0 + i] : -1;
    }

    // ---- stage x rows from f32 source, converting in flight ----
    // 4 threads/row, 16 floats each -> 16 bf16 shorts into LDS
    {
        const int row = tid >> 2;                // 0..63
        const int seg = (tid & 3) * 16;          // float offset in row
        const bool qside = row < 32;
        const int li = qside ? (q0 + row) : (q0 + row - 32);
        const bool valid = qside ? (do_q && li < nq) : (do_k && li < nk);
        if (valid) {
            int token = qside ? list_q[r * QCAP + li] : list_k[r * QCAP + li];
            int n = token >> 5, t = token & 31;
            const float* src = (t == 0)
                ? (curr_f + n * EE)
                : (msg + ((size_t)n * MM + (t - 1)) * EE);
            const float4* s4 = (const float4*)(src + seg);
            float4 f0 = s4[0], f1 = s4[1], f2 = s4[2], f3 = s4[3];
            unsigned short b[16] = {
                f2bf(f0.x), f2bf(f0.y), f2bf(f0.z), f2bf(f0.w),
                f2bf(f1.x), f2bf(f1.y), f2bf(f1.z), f2bf(f1.w),
                f2bf(f2.x), f2bf(f2.y), f2bf(f2.z), f2bf(f2.w),
                f2bf(f3.x), f2bf(f3.y), f2bf(f3.z), f2bf(f3.w) };
            unsigned short* d = &x_s[row * WSTR + seg];
            *(short8*)d = *(short8*)&b[0];
            *(short8*)(d + 8) = *(short8*)&b[8];
        }
    }
    __syncthreads();

    // ---- GEMM q/v (wave: mtile = w&1, mat = w>>1) ----
    if (do_q) {
        const int mtile = wave & 1;
        const unsigned short* w_s = (wave >> 1) ? wv_s : wq_s;
        unsigned short* outp = (wave >> 1) ? v_bf : q_bf;
        const int m = mtile * 16 + col;
        f32x4 acc[4] = {{0,0,0,0},{0,0,0,0},{0,0,0,0},{0,0,0,0}};
#pragma unroll
        for (int kk = 0; kk < 2; ++kk) {
            short8 af = *(const short8*)&x_s[m * WSTR + kk * 32 + quad * 8];
#pragma unroll
            for (int nt = 0; nt < 4; ++nt) {
                short8 bf = *(const short8*)&w_s[(nt * 16 + col) * WSTR + kk * 32 + quad * 8];
                acc[nt] = __builtin_amdgcn_mfma_f32_16x16x32_bf16(af, bf, acc[nt], 0, 0, 0);
            }
        }
#pragma unroll
        for (int nt = 0; nt < 4; ++nt)
#pragma unroll
            for (int reg = 0; reg < 4; ++reg) {
                int rrow = mtile * 16 + quad * 4 + reg;
                int token = tq_s[rrow];
                if (token >= 0)
                    outp[(size_t)token * EE + nt * 16 + col] = f2bf(acc[nt][reg]);
            }
    }

    // ---- GEMM k (wave: mtile = w&1, n-half = w>>1) ----
    if (do_k) {
        const int mtile = wave & 1;
        const int nh = wave >> 1;
        const int m = 32 + mtile * 16 + col;
        f32x4 acc[2] = {{0,0,0,0},{0,0,0,0}};
#pragma unroll
        for (int kk = 0; kk < 2; ++kk) {
            short8 af = *(const short8*)&x_s[m * WSTR + kk * 32 + quad * 8];
#pragma unroll
            for (int j = 0; j < 2; ++j) {
                int nt = nh * 2 + j;
                short8 bf = *(const short8*)&wk_s[(nt * 16 + col) * WSTR + kk * 32 + quad * 8];
                acc[j] = __builtin_amdgcn_mfma_f32_16x16x32_bf16(af, bf, acc[j], 0, 0, 0);
            }
        }
#pragma unroll
        for (int j = 0; j < 2; ++j)
#pragma unroll
            for (int reg = 0; reg < 4; ++reg) {
                int rrow = mtile * 16 + quad * 4 + reg;
                int token = tk_s[rrow];
                if (token >= 0)
                    k_bf[(size_t)token * EE + (nh * 2 + j) * 16 + col] = f2bf(acc[j][reg]);
            }
    }
}

// ---------------------------------------------------------------------------
// attn: one block per node; q/k/v are bf16 [32][64] rows, staged to f32 LDS.
// ---------------------------------------------------------------------------
__global__ __launch_bounds__(256) void attn_kernel(
    const unsigned short* __restrict__ q_bf,
    const unsigned short* __restrict__ k_bf,
    const unsigned short* __restrict__ v_bf,
    const float* __restrict__ ffn_w, const float* __restrict__ ffn_b,
    float* __restrict__ out)
{
    const int n = blockIdx.x, tid = threadIdx.x;
    __shared__ float q_s[TT][68], k_s[TT][68], v_s[TT][68];
    __shared__ float s_s[TT][TT + 1];
    __shared__ float att0[TT];
    __shared__ float pooled[EE];

    {   // stage + convert: thread -> one short8 per matrix (256 = 32 rows x 8)
        const int row = tid >> 3, c8 = (tid & 7) * 8;
        const size_t go = (size_t)n * TT * EE + row * EE + c8;
        short8 q8 = *(const short8*)(q_bf + go);
        short8 k8 = *(const short8*)(k_bf + go);
        short8 v8 = *(const short8*)(v_bf + go);
#pragma unroll
        for (int j = 0; j < 8; ++j) {
            q_s[row][c8 + j] = bf2f(((unsigned short*)&q8)[j]);
            k_s[row][c8 + j] = bf2f(((unsigned short*)&k8)[j]);
            v_s[row][c8 + j] = bf2f(((unsigned short*)&v8)[j]);
        }
    }
    __syncthreads();

    {   // scores s[qi][ki] = dot(q[qi],k[ki]) / 8
        const int ki = tid & 31;
        for (int qi = tid >> 5; qi < TT; qi += 8) {
            const float4* qp = (const float4*)&q_s[qi][0];
            const float4* kp = (const float4*)&k_s[ki][0];
            float acc = 0.f;
            for (int e4 = 0; e4 < EE / 4; ++e4) {
                float4 a = qp[e4], b = kp[e4];
                acc += a.x * b.x + a.y * b.y + a.z * b.z + a.w * b.w;
            }
            s_s[qi][ki] = acc * 0.125f;
        }
    }
    __syncthreads();

    // softmax over the QUERY axis per column; only row 0 of att needed
    if (tid < TT) {
        float mx = -INFINITY;
        for (int qi = 0; qi < TT; ++qi) mx = fmaxf(mx, s_s[qi][tid]);
        float sum = 0.f;
        for (int qi = 0; qi < TT; ++qi) sum += __expf(s_s[qi][tid] - mx);
        att0[tid] = __expf(s_s[0][tid] - mx) / sum;
    }
    __syncthreads();

    if (tid < EE) {
        float acc = 0.f;
        for (int ki = 0; ki < TT; ++ki)
            acc = fmaf(att0[ki], v_s[ki][tid], acc);
        pooled[tid] = acc;
    }
    __syncthreads();

    if (tid < EE) {
        float acc = ffn_b[tid];
        for (int a = 0; a < EE; ++a)
            acc = fmaf(pooled[a], ffn_w[a * EE + tid], acc);
        out[n * EE + tid] = acc;
    }
}

extern "C" void kernel_launch(void* const* d_in, const int* in_sizes, int n_in,
                              void* d_out, int out_size, void* d_ws, size_t ws_size,
                              hipStream_t stream) {
    const float* h            = (const float*)d_in[0];
    const float* msg          = (const float*)d_in[1];
    const int*   msg_type     = (const int*)  d_in[2];
    const int*   r_label_node = (const int*)  d_in[3];
    const int*   r_label_msg  = (const int*)  d_in[4];
    const float* W_self       = (const float*)d_in[5];
    const float* Q            = (const float*)d_in[6];
    const float* K            = (const float*)d_in[7];
    const float* V            = (const float*)d_in[8];
    const float* ffn_w        = (const float*)d_in[9];
    const float* ffn_b        = (const float*)d_in[10];
    float*       out          = (float*)d_out;

    // ws layout (16B aligned): counters | lists | bf16 weights | curr f32 | q/k/v
    int* cnt_q  = (int*)d_ws;                          // [200*CPAD]
    int* cnt_k  = cnt_q + NREL * CPAD;                 // [200*CPAD]
    int* list_q = cnt_k + NREL * CPAD;                 // [200*QCAP]
    int* list_k = list_q + NREL * QCAP;                // [200*QCAP]
    unsigned short* wt_q = (unsigned short*)(list_k + NREL * QCAP);
    unsigned short* wt_k = wt_q + (size_t)NMAT * EE * EE;
    unsigned short* wt_v = wt_k + (size_t)NMAT * EE * EE;
    float* curr_f = (float*)(wt_v + (size_t)NMAT * EE * EE);     // [512*64] f32
    unsigned short* q_bf = (unsigned short*)(curr_f + NN * EE);  // [512*32*64]
    unsigned short* k_bf = q_bf + (size_t)NN * TT * EE;
    unsigned short* v_bf = k_bf + (size_t)NN * TT * EE;

    hipMemsetAsync(cnt_q, 0, 2 * NREL * CPAD * sizeof(int), stream);
    prep_convert_kernel<<<3 * NMAT + NN, 256, 0, stream>>>(
        h, W_self, Q, K, V, msg_type, r_label_node, r_label_msg,
        cnt_q, cnt_k, list_q, list_k, wt_q, wt_k, wt_v,
        curr_f, k_bf);
    proj_tile_kernel<<<NREL * NT, 256, 0, stream>>>(
        curr_f, msg, wt_q, wt_k, wt_v, cnt_q, cnt_k, list_q, list_k,
        q_bf, k_bf, v_bf);
    attn_kernel<<<NN, 256, 0, stream>>>(q_bf, k_bf, v_bf, ffn_w, ffn_b, out);
}